// Round 1
// baseline (616.061 us; speedup 1.0000x reference)
//
#include <hip/hip_runtime.h>

// Graph transformer conv (TransformerConv-style) on MI355X.
// N=100000 nodes, E=1.6M edges, DIM=64, H=4, D=8.
// Pipeline: deg histogram -> fused QKV GEMM (q pre-scaled) -> single edge pass
// (no-max-subtraction softmax accumulation via atomics) -> normalize.

#define NDIM 64

__global__ void deg_hist_kernel(const int* __restrict__ s_arr,
                                int* __restrict__ deg, int E) {
    int i = blockIdx.x * blockDim.x + threadIdx.x;
    int stride = gridDim.x * blockDim.x;
    for (int e = i; e < E; e += stride)
        atomicAdd(&deg[s_arr[e]], 1);
}

// qkv = x @ W + b ; q scaled by 0.25 * deg^-0.5, split into qs/kk/vv.
// W (64x128) staged in LDS (32KB). 256 threads: 2 rows x 128 cols per iter.
__global__ void qkv_gemm_kernel(const float* __restrict__ x,
                                const float* __restrict__ W,
                                const float* __restrict__ b,
                                const int* __restrict__ deg,
                                float* __restrict__ qs,
                                float* __restrict__ kk,
                                float* __restrict__ vv, int N) {
    __shared__ float Wl[64 * 128];
    __shared__ float bl[128];
    __shared__ float xs[2][64];
    for (int i = threadIdx.x; i < 64 * 128; i += blockDim.x) Wl[i] = W[i];
    if (threadIdx.x < 128) bl[threadIdx.x] = b[threadIdx.x];
    __syncthreads();

    int col = threadIdx.x & 127;   // 0..127 output column
    int rw  = threadIdx.x >> 7;    // 0 or 1: which of the 2 rows

    for (int r0 = blockIdx.x * 2; r0 < N; r0 += gridDim.x * 2) {
        __syncthreads();           // protect xs from previous iteration
        if (threadIdx.x < 128) {
            int rr = threadIdx.x >> 6;
            int cc = threadIdx.x & 63;
            int n = r0 + rr;
            xs[rr][cc] = (n < N) ? x[(size_t)n * NDIM + cc] : 0.f;
        }
        __syncthreads();
        int n = r0 + rw;
        if (n < N) {
            float acc = bl[col];
            #pragma unroll
            for (int k = 0; k < 64; ++k)
                acc = fmaf(xs[rw][k], Wl[k * 128 + col], acc);
            if (col < 32) {
                // q scaled: QK_SCALE (=0.25) * deg^-0.5
                float dg = (float)deg[n];
                float sc = 0.25f * rsqrtf(dg);   // deg==0 -> inf, never read
                qs[(size_t)n * 32 + col] = acc * sc;
            } else if (col < 64) {
                kk[(size_t)n * 32 + (col - 32)] = acc;
            } else {
                vv[(size_t)n * 64 + (col - 64)] = acc;
            }
        }
    }
}

// One wave per edge (strided). Lane l owns v component l (head = l>>4).
// Lanes 0-31 compute q*k products; 8-lane butterfly gives compat[h].
// Accumulate exp(c)*v into out[s] (coalesced 256B atomic) and exp(c) into denom.
__global__ void edge_pass_kernel(const int* __restrict__ s_arr,
                                 const int* __restrict__ t_arr,
                                 const float* __restrict__ qs,
                                 const float* __restrict__ kk,
                                 const float* __restrict__ vv,
                                 float* __restrict__ out,
                                 float* __restrict__ denom, int E) {
    int lane = threadIdx.x & 63;
    int wid = (blockIdx.x * blockDim.x + threadIdx.x) >> 6;
    int nw  = (gridDim.x * blockDim.x) >> 6;
    for (int e = wid; e < E; e += nw) {
        int s = s_arr[e];
        int t = t_arr[e];
        float prod = 0.f;
        if (lane < 32)
            prod = qs[(size_t)s * 32 + lane] * kk[(size_t)t * 32 + lane];
        // reduce over d (8 lanes per head)
        prod += __shfl_xor(prod, 1);
        prod += __shfl_xor(prod, 2);
        prod += __shfl_xor(prod, 4);
        // broadcast compat[head] to the 16 lanes of each head
        float c = __shfl(prod, (lane >> 4) * 8);
        float w = __expf(c);
        float v = vv[(size_t)t * 64 + lane];
        atomicAdd(&out[(size_t)s * 64 + lane], w * v);
        // denom: lanes 0-3 accumulate head 0-3 (shfl executed by all lanes)
        float ch = __shfl(prod, (lane & 3) * 8);
        if (lane < 4)
            atomicAdd(&denom[(size_t)s * 4 + lane], __expf(ch));
    }
}

__global__ void normalize_kernel(float* __restrict__ out,
                                 const float* __restrict__ denom, int N) {
    int i = blockIdx.x * blockDim.x + threadIdx.x;
    int stride = gridDim.x * blockDim.x;
    int total = N * 64;
    for (int idx = i; idx < total; idx += stride) {
        int n = idx >> 6;
        int h = (idx >> 4) & 3;
        out[idx] = out[idx] / (denom[n * 4 + h] + 1e-16f);
    }
}

extern "C" void kernel_launch(void* const* d_in, const int* in_sizes, int n_in,
                              void* d_out, int out_size, void* d_ws, size_t ws_size,
                              hipStream_t stream) {
    const float* x = (const float*)d_in[0];
    const int*   eidx = (const int*)d_in[1];
    const float* W = (const float*)d_in[2];
    const float* b = (const float*)d_in[3];
    int N = in_sizes[0] / NDIM;
    int E = in_sizes[1] / 2;
    float* out = (float*)d_out;

    // workspace layout
    float* qs = (float*)d_ws;                  // N*32
    float* kk = qs + (size_t)N * 32;           // N*32
    float* vv = kk + (size_t)N * 32;           // N*64
    int*   deg = (int*)(vv + (size_t)N * 64);  // N ints
    float* denom = (float*)(deg + N);          // N*4 floats

    const int* s_arr = eidx;
    const int* t_arr = eidx + E;

    hipMemsetAsync(out, 0, (size_t)N * 64 * sizeof(float), stream);
    hipMemsetAsync(deg, 0, (size_t)N * sizeof(int) + (size_t)N * 4 * sizeof(float), stream);

    deg_hist_kernel<<<2048, 256, 0, stream>>>(s_arr, deg, E);
    qkv_gemm_kernel<<<2048, 256, 0, stream>>>(x, W, b, deg, qs, kk, vv, N);
    edge_pass_kernel<<<4096, 256, 0, stream>>>(s_arr, t_arr, qs, kk, vv, out, denom, E);
    normalize_kernel<<<2048, 256, 0, stream>>>(out, denom, N);
}

// Round 2
// 440.659 us; speedup vs baseline: 1.3980x; 1.3980x over previous
//
#include <hip/hip_runtime.h>

// Graph transformer conv on MI355X.
// N=100000, E=1.6M, DIM=64, H=4, D=8.
// Round 2: kill the 860 MB of atomic-RMW HBM traffic. Counting-sort edges by
// source node (deg -> block scan -> scatter), then wave-per-node aggregation
// with register accumulators and a single coalesced out-row write.

#define NDIM 64

__global__ void deg_hist_kernel(const int* __restrict__ s_arr,
                                int* __restrict__ deg, int E) {
    int i = blockIdx.x * blockDim.x + threadIdx.x;
    int stride = gridDim.x * blockDim.x;
    for (int e = i; e < E; e += stride)
        atomicAdd(&deg[s_arr[e]], 1);
}

// qkv = x @ W + b ; q scaled by 0.25 * deg^-0.5, split into qs/kk/vv.
__global__ void qkv_gemm_kernel(const float* __restrict__ x,
                                const float* __restrict__ W,
                                const float* __restrict__ b,
                                const int* __restrict__ deg,
                                float* __restrict__ qs,
                                float* __restrict__ kk,
                                float* __restrict__ vv, int N) {
    __shared__ float Wl[64 * 128];
    __shared__ float bl[128];
    __shared__ float xs[2][64];
    for (int i = threadIdx.x; i < 64 * 128; i += blockDim.x) Wl[i] = W[i];
    if (threadIdx.x < 128) bl[threadIdx.x] = b[threadIdx.x];
    __syncthreads();

    int col = threadIdx.x & 127;
    int rw  = threadIdx.x >> 7;

    for (int r0 = blockIdx.x * 2; r0 < N; r0 += gridDim.x * 2) {
        __syncthreads();
        if (threadIdx.x < 128) {
            int rr = threadIdx.x >> 6;
            int cc = threadIdx.x & 63;
            int n = r0 + rr;
            xs[rr][cc] = (n < N) ? x[(size_t)n * NDIM + cc] : 0.f;
        }
        __syncthreads();
        int n = r0 + rw;
        if (n < N) {
            float acc = bl[col];
            #pragma unroll
            for (int k = 0; k < 64; ++k)
                acc = fmaf(xs[rw][k], Wl[k * 128 + col], acc);
            if (col < 32) {
                float dg = (float)deg[n];
                float sc = 0.25f * rsqrtf(dg);   // deg==0 rows never read
                qs[(size_t)n * 32 + col] = acc * sc;
            } else if (col < 64) {
                kk[(size_t)n * 32 + (col - 32)] = acc;
            } else {
                vv[(size_t)n * 64 + (col - 64)] = acc;
            }
        }
    }
}

// Per-256-chunk inclusive scan of deg -> exclusive within block, block totals.
__global__ void scan_block_kernel(const int* __restrict__ deg,
                                  int* __restrict__ row_ptr,
                                  int* __restrict__ blk_sums, int N) {
    __shared__ int sh[256];
    int tid = threadIdx.x;
    int i = blockIdx.x * 256 + tid;
    int v = (i < N) ? deg[i] : 0;
    int acc = v;
    sh[tid] = acc;
    __syncthreads();
    for (int off = 1; off < 256; off <<= 1) {
        int add = (tid >= off) ? sh[tid - off] : 0;
        __syncthreads();
        acc += add;
        sh[tid] = acc;
        __syncthreads();
    }
    if (i < N) row_ptr[i] = acc - v;           // block-local exclusive
    if (tid == 255) blk_sums[blockIdx.x] = acc; // block total
}

// Scan the (<=512) block totals in one block -> exclusive offsets in place.
__global__ void scan_top_kernel(int* __restrict__ blk_sums, int nblk) {
    __shared__ int sh[512];
    int tid = threadIdx.x;
    int v = (tid < nblk) ? blk_sums[tid] : 0;
    int acc = v;
    sh[tid] = acc;
    __syncthreads();
    for (int off = 1; off < 512; off <<= 1) {
        int add = (tid >= off) ? sh[tid - off] : 0;
        __syncthreads();
        acc += add;
        sh[tid] = acc;
        __syncthreads();
    }
    if (tid < nblk) blk_sums[tid] = acc - v;   // exclusive
}

__global__ void add_offsets_kernel(int* __restrict__ row_ptr,
                                   const int* __restrict__ blk_sums,
                                   int* __restrict__ cursor, int N) {
    int i = blockIdx.x * 256 + threadIdx.x;
    if (i < N) {
        int r = row_ptr[i] + blk_sums[i >> 8];
        row_ptr[i] = r;
        cursor[i] = r;
    }
}

__global__ void scatter_kernel(const int* __restrict__ s_arr,
                               const int* __restrict__ t_arr,
                               int* __restrict__ cursor,
                               int* __restrict__ sorted_t, int E) {
    int i = blockIdx.x * blockDim.x + threadIdx.x;
    int stride = gridDim.x * blockDim.x;
    for (int e = i; e < E; e += stride) {
        int s = s_arr[e];
        int pos = atomicAdd(&cursor[s], 1);
        sorted_t[pos] = t_arr[e];
    }
}

// One wave per node. Lane l owns out component l (head = l>>4).
// q held in registers; 2-way unrolled edge loop; register denom; single write.
__global__ void aggregate_kernel(const int* __restrict__ row_ptr,
                                 const int* __restrict__ deg,
                                 const int* __restrict__ sorted_t,
                                 const float* __restrict__ qs,
                                 const float* __restrict__ kk,
                                 const float* __restrict__ vv,
                                 float* __restrict__ out, int N) {
    int lane = threadIdx.x & 63;
    int n = (blockIdx.x * blockDim.x + threadIdx.x) >> 6;
    if (n >= N) return;
    int start = row_ptr[n];
    int end = start + deg[n];
    float q = (lane < 32) ? qs[(size_t)n * 32 + lane] : 0.f;
    float acc = 0.f, den = 0.f;
    int j = start;
    for (; j + 1 < end; j += 2) {
        int t0 = sorted_t[j], t1 = sorted_t[j + 1];
        float k0 = (lane < 32) ? kk[(size_t)t0 * 32 + lane] : 0.f;
        float k1 = (lane < 32) ? kk[(size_t)t1 * 32 + lane] : 0.f;
        float v0 = vv[(size_t)t0 * 64 + lane];
        float v1 = vv[(size_t)t1 * 64 + lane];
        float p0 = q * k0, p1 = q * k1;
        p0 += __shfl_xor(p0, 1); p0 += __shfl_xor(p0, 2); p0 += __shfl_xor(p0, 4);
        p1 += __shfl_xor(p1, 1); p1 += __shfl_xor(p1, 2); p1 += __shfl_xor(p1, 4);
        float c0 = __shfl(p0, (lane >> 4) * 8);
        float c1 = __shfl(p1, (lane >> 4) * 8);
        float w0 = __expf(c0), w1 = __expf(c1);
        acc = fmaf(w0, v0, acc);
        acc = fmaf(w1, v1, acc);
        den += w0 + w1;
    }
    if (j < end) {
        int t0 = sorted_t[j];
        float k0 = (lane < 32) ? kk[(size_t)t0 * 32 + lane] : 0.f;
        float v0 = vv[(size_t)t0 * 64 + lane];
        float p0 = q * k0;
        p0 += __shfl_xor(p0, 1); p0 += __shfl_xor(p0, 2); p0 += __shfl_xor(p0, 4);
        float c0 = __shfl(p0, (lane >> 4) * 8);
        float w0 = __expf(c0);
        acc = fmaf(w0, v0, acc);
        den += w0;
    }
    out[(size_t)n * 64 + lane] = acc / (den + 1e-16f);
}

extern "C" void kernel_launch(void* const* d_in, const int* in_sizes, int n_in,
                              void* d_out, int out_size, void* d_ws, size_t ws_size,
                              hipStream_t stream) {
    const float* x = (const float*)d_in[0];
    const int*   eidx = (const int*)d_in[1];
    const float* W = (const float*)d_in[2];
    const float* b = (const float*)d_in[3];
    int N = in_sizes[0] / NDIM;
    int E = in_sizes[1] / 2;
    float* out = (float*)d_out;

    int nblk = (N + 255) / 256;   // 391 for N=100000 (must be <= 512)

    // workspace layout
    float* qs = (float*)d_ws;                       // N*32 f
    float* kk = qs + (size_t)N * 32;                // N*32 f
    float* vv = kk + (size_t)N * 32;                // N*64 f
    int* deg      = (int*)(vv + (size_t)N * 64);    // N int
    int* row_ptr  = deg + N;                        // N int
    int* cursor   = row_ptr + N;                    // N int
    int* blk_sums = cursor + N;                     // 512 int
    int* sorted_t = blk_sums + 512;                 // E int

    const int* s_arr = eidx;
    const int* t_arr = eidx + E;

    hipMemsetAsync(deg, 0, (size_t)N * sizeof(int), stream);

    deg_hist_kernel<<<2048, 256, 0, stream>>>(s_arr, deg, E);
    qkv_gemm_kernel<<<2048, 256, 0, stream>>>(x, W, b, deg, qs, kk, vv, N);
    scan_block_kernel<<<nblk, 256, 0, stream>>>(deg, row_ptr, blk_sums, N);
    scan_top_kernel<<<1, 512, 0, stream>>>(blk_sums, nblk);
    add_offsets_kernel<<<nblk, 256, 0, stream>>>(row_ptr, blk_sums, cursor, N);
    scatter_kernel<<<2048, 256, 0, stream>>>(s_arr, t_arr, cursor, sorted_t, E);
    aggregate_kernel<<<(N + 3) / 4, 256, 0, stream>>>(row_ptr, deg, sorted_t,
                                                      qs, kk, vv, out, N);
}

// Round 3
// 399.411 us; speedup vs baseline: 1.5424x; 1.1033x over previous
//
#include <hip/hip_runtime.h>

// Graph transformer conv on MI355X. N=100000, E=1.6M, DIM=64, H=4, D=8.
// Round 3: halve gather bytes. k+v packed per node as one 192-B bf16 record
// (32 bf16 k + 64 bf16 v). Aggregate: lanes 0-15 own k-pairs, lanes 16-47 own
// v-pairs; one 4-B load per lane per edge; per-lane denom; float2 out write.

#define NDIM 64

static __device__ __forceinline__ unsigned short f2bf(float f) {
    unsigned int u = __float_as_uint(f);
    unsigned int r = (u + 0x7fffu + ((u >> 16) & 1u)) >> 16;  // RNE
    return (unsigned short)r;
}

__global__ void deg_hist_kernel(const int* __restrict__ s_arr,
                                int* __restrict__ deg, int E) {
    int i = blockIdx.x * blockDim.x + threadIdx.x;
    int stride = gridDim.x * blockDim.x;
    for (int e = i; e < E; e += stride)
        atomicAdd(&deg[s_arr[e]], 1);
}

// qkv = x @ W + b ; q scaled by 0.25*deg^-0.5 (fp32, 32 f/node);
// k,v -> packed bf16 record kv[n*96 .. n*96+95] (ushort): [0,32)=k, [32,96)=v.
__global__ void qkv_gemm_kernel(const float* __restrict__ x,
                                const float* __restrict__ W,
                                const float* __restrict__ b,
                                const int* __restrict__ deg,
                                float* __restrict__ qs,
                                unsigned short* __restrict__ kv, int N) {
    __shared__ float Wl[64 * 128];
    __shared__ float bl[128];
    __shared__ float xs[2][64];
    for (int i = threadIdx.x; i < 64 * 128; i += blockDim.x) Wl[i] = W[i];
    if (threadIdx.x < 128) bl[threadIdx.x] = b[threadIdx.x];
    __syncthreads();

    int col = threadIdx.x & 127;
    int rw  = threadIdx.x >> 7;

    for (int r0 = blockIdx.x * 2; r0 < N; r0 += gridDim.x * 2) {
        __syncthreads();
        if (threadIdx.x < 128) {
            int rr = threadIdx.x >> 6;
            int cc = threadIdx.x & 63;
            int n = r0 + rr;
            xs[rr][cc] = (n < N) ? x[(size_t)n * NDIM + cc] : 0.f;
        }
        __syncthreads();
        int n = r0 + rw;
        if (n < N) {
            float acc = bl[col];
            #pragma unroll
            for (int k = 0; k < 64; ++k)
                acc = fmaf(xs[rw][k], Wl[k * 128 + col], acc);
            if (col < 32) {
                float dg = (float)deg[n];
                float sc = 0.25f * rsqrtf(dg);   // deg==0 rows never read
                qs[(size_t)n * 32 + col] = acc * sc;
            } else if (col < 64) {
                kv[(size_t)n * 96 + (col - 32)] = f2bf(acc);
            } else {
                kv[(size_t)n * 96 + 32 + (col - 64)] = f2bf(acc);
            }
        }
    }
}

__global__ void scan_block_kernel(const int* __restrict__ deg,
                                  int* __restrict__ row_ptr,
                                  int* __restrict__ blk_sums, int N) {
    __shared__ int sh[256];
    int tid = threadIdx.x;
    int i = blockIdx.x * 256 + tid;
    int v = (i < N) ? deg[i] : 0;
    int acc = v;
    sh[tid] = acc;
    __syncthreads();
    for (int off = 1; off < 256; off <<= 1) {
        int add = (tid >= off) ? sh[tid - off] : 0;
        __syncthreads();
        acc += add;
        sh[tid] = acc;
        __syncthreads();
    }
    if (i < N) row_ptr[i] = acc - v;
    if (tid == 255) blk_sums[blockIdx.x] = acc;
}

__global__ void scan_top_kernel(int* __restrict__ blk_sums, int nblk) {
    __shared__ int sh[512];
    int tid = threadIdx.x;
    int v = (tid < nblk) ? blk_sums[tid] : 0;
    int acc = v;
    sh[tid] = acc;
    __syncthreads();
    for (int off = 1; off < 512; off <<= 1) {
        int add = (tid >= off) ? sh[tid - off] : 0;
        __syncthreads();
        acc += add;
        sh[tid] = acc;
        __syncthreads();
    }
    if (tid < nblk) blk_sums[tid] = acc - v;
}

__global__ void add_offsets_kernel(int* __restrict__ row_ptr,
                                   const int* __restrict__ blk_sums,
                                   int* __restrict__ cursor, int N) {
    int i = blockIdx.x * 256 + threadIdx.x;
    if (i < N) {
        int r = row_ptr[i] + blk_sums[i >> 8];
        row_ptr[i] = r;
        cursor[i] = r;
    }
}

__global__ void scatter_kernel(const int* __restrict__ s_arr,
                               const int* __restrict__ t_arr,
                               int* __restrict__ cursor,
                               int* __restrict__ sorted_t, int E) {
    int i = blockIdx.x * blockDim.x + threadIdx.x;
    int stride = gridDim.x * blockDim.x;
    for (int e = i; e < E; e += stride) {
        int s = s_arr[e];
        int pos = atomicAdd(&cursor[s], 1);
        sorted_t[pos] = t_arr[e];
    }
}

// One wave per node. Record = 48 uints (192 B): [0,16)=k pairs, [16,48)=v pairs.
// Lane l<16: k pair l (q dot via 2 xor-shfls in 4-lane clusters; head = l>>2).
// Lane 16..47: v pair (l-16), head = (l-16)>>3; per-lane denom; float2 write.
__global__ void aggregate_kernel(const int* __restrict__ row_ptr,
                                 const int* __restrict__ deg,
                                 const int* __restrict__ sorted_t,
                                 const float* __restrict__ qs,
                                 const unsigned int* __restrict__ kv32,
                                 float* __restrict__ out, int N) {
    int lane = threadIdx.x & 63;
    int n = (blockIdx.x * blockDim.x + threadIdx.x) >> 6;
    if (n >= N) return;
    int start = row_ptr[n];
    int end = start + deg[n];

    // q pair for lanes 0-15
    float q0 = 0.f, q1 = 0.f;
    if (lane < 16) {
        q0 = qs[(size_t)n * 32 + 2 * lane];
        q1 = qs[(size_t)n * 32 + 2 * lane + 1];
    }
    // shfl source for compat broadcast: lanes<16 use own cluster base,
    // lanes 16..47 use head cluster base, lanes 48+ dummy.
    int csrc = (lane < 16) ? (lane & ~3)
             : (lane < 48) ? (((lane - 16) >> 3) << 2)
                           : 0;

    float accx = 0.f, accy = 0.f, den = 0.f;
    int j = start;
    for (; j + 1 < end; j += 2) {
        int t0 = sorted_t[j], t1 = sorted_t[j + 1];
        unsigned int r0 = 0, r1 = 0;
        if (lane < 48) {
            r0 = kv32[(size_t)t0 * 48 + lane];
            r1 = kv32[(size_t)t1 * 48 + lane];
        }
        float lo0 = __uint_as_float(r0 << 16);
        float hi0 = __uint_as_float(r0 & 0xffff0000u);
        float lo1 = __uint_as_float(r1 << 16);
        float hi1 = __uint_as_float(r1 & 0xffff0000u);
        float p0 = fmaf(q0, lo0, q1 * hi0);
        float p1 = fmaf(q0, lo1, q1 * hi1);
        p0 += __shfl_xor(p0, 1); p0 += __shfl_xor(p0, 2);
        p1 += __shfl_xor(p1, 1); p1 += __shfl_xor(p1, 2);
        float c0 = __shfl(p0, csrc);
        float c1 = __shfl(p1, csrc);
        float w0 = __expf(c0), w1 = __expf(c1);
        accx = fmaf(w0, lo0, accx); accy = fmaf(w0, hi0, accy);
        accx = fmaf(w1, lo1, accx); accy = fmaf(w1, hi1, accy);
        den += w0 + w1;
    }
    if (j < end) {
        int t0 = sorted_t[j];
        unsigned int r0 = 0;
        if (lane < 48) r0 = kv32[(size_t)t0 * 48 + lane];
        float lo0 = __uint_as_float(r0 << 16);
        float hi0 = __uint_as_float(r0 & 0xffff0000u);
        float p0 = fmaf(q0, lo0, q1 * hi0);
        p0 += __shfl_xor(p0, 1); p0 += __shfl_xor(p0, 2);
        float c0 = __shfl(p0, csrc);
        float w0 = __expf(c0);
        accx = fmaf(w0, lo0, accx); accy = fmaf(w0, hi0, accy);
        den += w0;
    }
    if (lane >= 16 && lane < 48) {
        float inv = 1.0f / (den + 1e-16f);
        float2 o = make_float2(accx * inv, accy * inv);
        *reinterpret_cast<float2*>(&out[(size_t)n * 64 + 2 * (lane - 16)]) = o;
    }
}

extern "C" void kernel_launch(void* const* d_in, const int* in_sizes, int n_in,
                              void* d_out, int out_size, void* d_ws, size_t ws_size,
                              hipStream_t stream) {
    const float* x = (const float*)d_in[0];
    const int*   eidx = (const int*)d_in[1];
    const float* W = (const float*)d_in[2];
    const float* b = (const float*)d_in[3];
    int N = in_sizes[0] / NDIM;
    int E = in_sizes[1] / 2;
    float* out = (float*)d_out;

    int nblk = (N + 255) / 256;   // must be <= 512

    // workspace layout
    float* qs = (float*)d_ws;                         // N*32 f
    unsigned short* kv = (unsigned short*)(qs + (size_t)N * 32);  // N*96 u16
    int* deg      = (int*)(kv + (size_t)N * 96);      // N int
    int* row_ptr  = deg + N;                          // N int
    int* cursor   = row_ptr + N;                      // N int
    int* blk_sums = cursor + N;                       // 512 int
    int* sorted_t = blk_sums + 512;                   // E int

    const int* s_arr = eidx;
    const int* t_arr = eidx + E;

    hipMemsetAsync(deg, 0, (size_t)N * sizeof(int), stream);

    deg_hist_kernel<<<2048, 256, 0, stream>>>(s_arr, deg, E);
    qkv_gemm_kernel<<<2048, 256, 0, stream>>>(x, W, b, deg, qs, kv, N);
    scan_block_kernel<<<nblk, 256, 0, stream>>>(deg, row_ptr, blk_sums, N);
    scan_top_kernel<<<1, 512, 0, stream>>>(blk_sums, nblk);
    add_offsets_kernel<<<nblk, 256, 0, stream>>>(row_ptr, blk_sums, cursor, N);
    scatter_kernel<<<2048, 256, 0, stream>>>(s_arr, t_arr, cursor, sorted_t, E);
    aggregate_kernel<<<(N + 3) / 4, 256, 0, stream>>>(
        row_ptr, deg, sorted_t, qs, (const unsigned int*)kv, out, N);
}

// Round 4
// 229.453 us; speedup vs baseline: 2.6849x; 1.7407x over previous
//
#include <hip/hip_runtime.h>

// Graph transformer conv on MI355X. N=100000, E=1.6M, DIM=64, H=4, D=8.
// Round 4: kill scattered-write amplification. Two-level bucket sort
// (128-node buckets): tile-local LDS counting sort + chunk-coalesced bucket
// append, then per-bucket LDS sort emitting deg/row_ptr/sorted_t coalesced.
// Also: GEMM with W in registers + x broadcast from LDS (64x less LDS traffic).

#define NDIM 64
#define NBMAX 1024      // buckets of 128 nodes; s < 2^17 -> bucket < 1024
#define CTILE 8192

static __device__ __forceinline__ unsigned short f2bf(float f) {
    unsigned int u = __float_as_uint(f);
    unsigned int r = (u + 0x7fffu + ((u >> 16) & 1u)) >> 16;  // RNE
    return (unsigned short)r;
}

// ---- 1. count edges per 128-node bucket --------------------------------
__global__ void bucket_count_kernel(const int* __restrict__ s_arr,
                                    unsigned int* __restrict__ bcnt, int E) {
    __shared__ unsigned int h[NBMAX];
    for (int i = threadIdx.x; i < NBMAX; i += blockDim.x) h[i] = 0;
    __syncthreads();
    int i0 = blockIdx.x * blockDim.x + threadIdx.x;
    int st = gridDim.x * blockDim.x;
    for (int e = i0; e < E; e += st)
        atomicAdd(&h[(unsigned)s_arr[e] >> 7], 1u);
    __syncthreads();
    for (int i = threadIdx.x; i < NBMAX; i += blockDim.x)
        if (h[i]) atomicAdd(&bcnt[i], h[i]);
}

// ---- 2. exclusive scan of bucket counts (single 1024-thread block) -----
__global__ void scan_buckets_kernel(const unsigned int* __restrict__ bcnt,
                                    unsigned int* __restrict__ bbase,
                                    unsigned int* __restrict__ gcur) {
    __shared__ unsigned int sh[1024];
    int tid = threadIdx.x;
    unsigned int v = bcnt[tid];
    unsigned int acc = v;
    sh[tid] = acc;
    __syncthreads();
    for (int off = 1; off < 1024; off <<= 1) {
        unsigned int add = (tid >= off) ? sh[tid - off] : 0;
        __syncthreads();
        acc += add;
        sh[tid] = acc;
        __syncthreads();
    }
    bbase[tid] = acc - v;
    gcur[tid]  = acc - v;
}

// ---- 3. bin edges into bucket-major order, chunk-coalesced -------------
// Each 512-thread block: local counting sort of an 8192-edge tile by bucket
// in LDS, then per-bucket global reservation + wave-coalesced segment copy.
__global__ void bin_kernel(const int* __restrict__ s_arr,
                           const int* __restrict__ t_arr,
                           unsigned int* __restrict__ gcur,
                           unsigned int* __restrict__ binned, int E) {
    __shared__ unsigned int hist[NBMAX];
    __shared__ unsigned int off[NBMAX];
    __shared__ unsigned int gbase[NBMAX];
    __shared__ unsigned int stg[CTILE];
    __shared__ unsigned int psum[512];
    int tid = threadIdx.x;
    int e0 = blockIdx.x * CTILE;
    int cnt = min(CTILE, E - e0);

    for (int i = tid; i < NBMAX; i += 512) hist[i] = 0;
    __syncthreads();
    for (int i = tid; i < cnt; i += 512)
        atomicAdd(&hist[(unsigned)s_arr[e0 + i] >> 7], 1u);
    __syncthreads();

    // exclusive scan of hist[1024] via 512 pair-sums
    unsigned int a0 = hist[2 * tid];
    unsigned int a1 = hist[2 * tid + 1];
    unsigned int ps = a0 + a1;
    unsigned int acc = ps;
    psum[tid] = acc;
    __syncthreads();
    for (int o = 1; o < 512; o <<= 1) {
        unsigned int add = (tid >= o) ? psum[tid - o] : 0;
        __syncthreads();
        acc += add;
        psum[tid] = acc;
        __syncthreads();
    }
    unsigned int exc = acc - ps;
    off[2 * tid]     = exc;
    off[2 * tid + 1] = exc + a0;
    __syncthreads();

    // scatter tile into stg, bucket-major
    for (int i = tid; i < cnt; i += 512) {
        int s = s_arr[e0 + i];
        int t = t_arr[e0 + i];
        unsigned int bkt = (unsigned)s >> 7;
        unsigned int p = atomicAdd(&off[bkt], 1u);
        stg[p] = ((unsigned)(s & 127) << 17) | (unsigned)t;
    }
    __syncthreads();

    // reserve global ranges (one atomic per non-empty bucket)
    for (int i = tid; i < NBMAX; i += 512) {
        unsigned int h = hist[i];
        gbase[i] = h ? atomicAdd(&gcur[i], h) : 0u;
    }
    __syncthreads();

    // wave-coalesced copy of each bucket segment (off[b] is now segment end)
    int wid = tid >> 6, lane = tid & 63;
    for (int b = wid; b < NBMAX; b += 8) {
        unsigned int h = hist[b];
        if (h == 0) continue;
        unsigned int src = off[b] - h;
        unsigned int dst = gbase[b];
        for (unsigned int i = lane; i < h; i += 64)
            binned[dst + i] = stg[src + i];
    }
}

// ---- 4. per-bucket counting sort -> deg, row_ptr, sorted_t -------------
// sorted_t aliases binned (reads complete before writes, same block/segment).
__global__ void bucket_sort_kernel(const unsigned int* __restrict__ bbase,
                                   const unsigned int* __restrict__ bcnt,
                                   unsigned int* __restrict__ binned,
                                   int* __restrict__ deg,
                                   int* __restrict__ row_ptr, int N) {
    __shared__ unsigned int hist[128];
    __shared__ unsigned int cur[128];
    __shared__ unsigned int stg[4096];
    int b = blockIdx.x;
    int tid = threadIdx.x;
    unsigned int base = bbase[b];
    unsigned int cnt = bcnt[b];

    if (tid < 128) hist[tid] = 0;
    __syncthreads();
    for (unsigned int i = tid; i < cnt; i += 256)
        atomicAdd(&hist[binned[base + i] >> 17], 1u);
    __syncthreads();

    // exclusive scan of hist[128] (first 128 threads), uniform barriers
    __shared__ unsigned int sh[128];
    unsigned int v = (tid < 128) ? hist[tid] : 0;
    unsigned int acc = v;
    if (tid < 128) sh[tid] = acc;
    __syncthreads();
    for (int o = 1; o < 128; o <<= 1) {
        unsigned int add = (tid >= o && tid < 128) ? sh[tid - o] : 0;
        __syncthreads();
        if (tid < 128) { acc += add; sh[tid] = acc; }
        __syncthreads();
    }
    if (tid < 128) {
        unsigned int exc = acc - v;
        cur[tid] = exc;
        int n = b * 128 + tid;
        if (n < N) { deg[n] = (int)v; row_ptr[n] = (int)(base + exc); }
    }
    __syncthreads();

    for (unsigned int i = tid; i < cnt; i += 256) {
        unsigned int e = binned[base + i];
        unsigned int p = atomicAdd(&cur[e >> 17], 1u);
        stg[p] = e & 0x1FFFFu;
    }
    __syncthreads();
    for (unsigned int i = tid; i < cnt; i += 256)
        binned[base + i] = stg[i];          // binned now == sorted_t
}

// ---- 5. qkv GEMM: W column in regs, x broadcast from LDS ---------------
__global__ void qkv_gemm_kernel(const float* __restrict__ x,
                                const float* __restrict__ W,
                                const float* __restrict__ b,
                                const int* __restrict__ deg,
                                float* __restrict__ qs,
                                unsigned short* __restrict__ kv, int N) {
    int col = threadIdx.x & 127;
    int rw  = threadIdx.x >> 7;
    float w[64];
    #pragma unroll
    for (int k = 0; k < 64; ++k) w[k] = W[k * 128 + col];
    float bias = b[col];
    __shared__ float4 xs[2][16];

    for (int r0 = blockIdx.x * 2; r0 < N; r0 += gridDim.x * 2) {
        __syncthreads();
        if (threadIdx.x < 32) {
            int rr = threadIdx.x >> 4;
            int cc = threadIdx.x & 15;
            int n = r0 + rr;
            xs[rr][cc] = (n < N)
                ? reinterpret_cast<const float4*>(x)[(size_t)n * 16 + cc]
                : make_float4(0.f, 0.f, 0.f, 0.f);
        }
        __syncthreads();
        int n = r0 + rw;
        if (n < N) {
            float acc = bias;
            #pragma unroll
            for (int k4 = 0; k4 < 16; ++k4) {
                float4 xv = xs[rw][k4];
                acc = fmaf(xv.x, w[4 * k4 + 0], acc);
                acc = fmaf(xv.y, w[4 * k4 + 1], acc);
                acc = fmaf(xv.z, w[4 * k4 + 2], acc);
                acc = fmaf(xv.w, w[4 * k4 + 3], acc);
            }
            if (col < 32) {
                float dg = (float)deg[n];
                float sc = 0.25f * rsqrtf(dg);   // deg==0 rows never read
                qs[(size_t)n * 32 + col] = acc * sc;
            } else if (col < 64) {
                kv[(size_t)n * 96 + (col - 32)] = f2bf(acc);
            } else {
                kv[(size_t)n * 96 + 32 + (col - 64)] = f2bf(acc);
            }
        }
    }
}

// ---- 6. aggregate (unchanged from round 3) -----------------------------
__global__ void aggregate_kernel(const int* __restrict__ row_ptr,
                                 const int* __restrict__ deg,
                                 const int* __restrict__ sorted_t,
                                 const float* __restrict__ qs,
                                 const unsigned int* __restrict__ kv32,
                                 float* __restrict__ out, int N) {
    int lane = threadIdx.x & 63;
    int n = (blockIdx.x * blockDim.x + threadIdx.x) >> 6;
    if (n >= N) return;
    int start = row_ptr[n];
    int end = start + deg[n];

    float q0 = 0.f, q1 = 0.f;
    if (lane < 16) {
        q0 = qs[(size_t)n * 32 + 2 * lane];
        q1 = qs[(size_t)n * 32 + 2 * lane + 1];
    }
    int csrc = (lane < 16) ? (lane & ~3)
             : (lane < 48) ? (((lane - 16) >> 3) << 2)
                           : 0;

    float accx = 0.f, accy = 0.f, den = 0.f;
    int j = start;
    for (; j + 1 < end; j += 2) {
        int t0 = sorted_t[j], t1 = sorted_t[j + 1];
        unsigned int r0 = 0, r1 = 0;
        if (lane < 48) {
            r0 = kv32[(size_t)t0 * 48 + lane];
            r1 = kv32[(size_t)t1 * 48 + lane];
        }
        float lo0 = __uint_as_float(r0 << 16);
        float hi0 = __uint_as_float(r0 & 0xffff0000u);
        float lo1 = __uint_as_float(r1 << 16);
        float hi1 = __uint_as_float(r1 & 0xffff0000u);
        float p0 = fmaf(q0, lo0, q1 * hi0);
        float p1 = fmaf(q0, lo1, q1 * hi1);
        p0 += __shfl_xor(p0, 1); p0 += __shfl_xor(p0, 2);
        p1 += __shfl_xor(p1, 1); p1 += __shfl_xor(p1, 2);
        float c0 = __shfl(p0, csrc);
        float c1 = __shfl(p1, csrc);
        float w0 = __expf(c0), w1 = __expf(c1);
        accx = fmaf(w0, lo0, accx); accy = fmaf(w0, hi0, accy);
        accx = fmaf(w1, lo1, accx); accy = fmaf(w1, hi1, accy);
        den += w0 + w1;
    }
    if (j < end) {
        int t0 = sorted_t[j];
        unsigned int r0 = 0;
        if (lane < 48) r0 = kv32[(size_t)t0 * 48 + lane];
        float lo0 = __uint_as_float(r0 << 16);
        float hi0 = __uint_as_float(r0 & 0xffff0000u);
        float p0 = fmaf(q0, lo0, q1 * hi0);
        p0 += __shfl_xor(p0, 1); p0 += __shfl_xor(p0, 2);
        float c0 = __shfl(p0, csrc);
        float w0 = __expf(c0);
        accx = fmaf(w0, lo0, accx); accy = fmaf(w0, hi0, accy);
        den += w0;
    }
    if (lane >= 16 && lane < 48) {
        float inv = 1.0f / (den + 1e-16f);
        float2 o = make_float2(accx * inv, accy * inv);
        *reinterpret_cast<float2*>(&out[(size_t)n * 64 + 2 * (lane - 16)]) = o;
    }
}

extern "C" void kernel_launch(void* const* d_in, const int* in_sizes, int n_in,
                              void* d_out, int out_size, void* d_ws, size_t ws_size,
                              hipStream_t stream) {
    const float* x = (const float*)d_in[0];
    const int*   eidx = (const int*)d_in[1];
    const float* W = (const float*)d_in[2];
    const float* b = (const float*)d_in[3];
    int N = in_sizes[0] / NDIM;
    int E = in_sizes[1] / 2;
    float* out = (float*)d_out;

    int NB = (N + 127) / 128;           // 782, must be <= NBMAX

    // workspace layout
    float* qs = (float*)d_ws;                                     // N*32 f
    unsigned short* kv = (unsigned short*)(qs + (size_t)N * 32);  // N*96 u16
    int* deg      = (int*)(kv + (size_t)N * 96);                  // N int
    int* row_ptr  = deg + N;                                      // N int
    unsigned int* bcnt  = (unsigned int*)(row_ptr + N);           // NBMAX
    unsigned int* bbase = bcnt + NBMAX;                           // NBMAX
    unsigned int* gcur  = bbase + NBMAX;                          // NBMAX
    unsigned int* binned = gcur + NBMAX;                          // E u32 (aliases sorted_t)

    const int* s_arr = eidx;
    const int* t_arr = eidx + E;

    hipMemsetAsync(bcnt, 0, NBMAX * sizeof(unsigned int), stream);

    bucket_count_kernel<<<256, 256, 0, stream>>>(s_arr, bcnt, E);
    scan_buckets_kernel<<<1, 1024, 0, stream>>>(bcnt, bbase, gcur);
    bin_kernel<<<(E + CTILE - 1) / CTILE, 512, 0, stream>>>(s_arr, t_arr, gcur, binned, E);
    bucket_sort_kernel<<<NB, 256, 0, stream>>>(bbase, bcnt, binned, deg, row_ptr, N);
    qkv_gemm_kernel<<<2048, 256, 0, stream>>>(x, W, b, deg, qs, kv, N);
    aggregate_kernel<<<(N + 3) / 4, 256, 0, stream>>>(
        row_ptr, deg, (const int*)binned, qs, (const unsigned int*)kv, out, N);
}

// Round 5
// 196.142 us; speedup vs baseline: 3.1409x; 1.1698x over previous
//
#include <hip/hip_runtime.h>

// Graph transformer conv on MI355X. N=100000, E=1.6M, DIM=64, H=4, D=8.
// Round 5: fuse per-bucket counting sort INTO aggregate (sort in LDS, no
// global sorted_t round-trip), 4-wide gather pipeline, deg-scaling moved to
// aggregate so GEMM is independent of the sort chain.

#define NDIM 64
#define NBMAX 1024      // buckets of 128 nodes
#define CTILE 8192
#define STGMAX 4352     // per-bucket edge capacity (mean 2048, sd ~45)

static __device__ __forceinline__ unsigned short f2bf(float f) {
    unsigned int u = __float_as_uint(f);
    unsigned int r = (u + 0x7fffu + ((u >> 16) & 1u)) >> 16;  // RNE
    return (unsigned short)r;
}

// ---- 1. count edges per 128-node bucket --------------------------------
__global__ void bucket_count_kernel(const int* __restrict__ s_arr,
                                    unsigned int* __restrict__ bcnt, int E) {
    __shared__ unsigned int h[NBMAX];
    for (int i = threadIdx.x; i < NBMAX; i += blockDim.x) h[i] = 0;
    __syncthreads();
    int i0 = blockIdx.x * blockDim.x + threadIdx.x;
    int st = gridDim.x * blockDim.x;
    for (int e = i0; e < E; e += st)
        atomicAdd(&h[(unsigned)s_arr[e] >> 7], 1u);
    __syncthreads();
    for (int i = threadIdx.x; i < NBMAX; i += blockDim.x)
        if (h[i]) atomicAdd(&bcnt[i], h[i]);
}

// ---- 2. exclusive scan of bucket counts --------------------------------
__global__ void scan_buckets_kernel(const unsigned int* __restrict__ bcnt,
                                    unsigned int* __restrict__ bbase,
                                    unsigned int* __restrict__ gcur) {
    __shared__ unsigned int sh[1024];
    int tid = threadIdx.x;
    unsigned int v = bcnt[tid];
    unsigned int acc = v;
    sh[tid] = acc;
    __syncthreads();
    for (int off = 1; off < 1024; off <<= 1) {
        unsigned int add = (tid >= off) ? sh[tid - off] : 0;
        __syncthreads();
        acc += add;
        sh[tid] = acc;
        __syncthreads();
    }
    bbase[tid] = acc - v;
    gcur[tid]  = acc - v;
}

// ---- 3. bin edges into bucket-major order, chunk-coalesced -------------
__global__ void bin_kernel(const int* __restrict__ s_arr,
                           const int* __restrict__ t_arr,
                           unsigned int* __restrict__ gcur,
                           unsigned int* __restrict__ binned, int E) {
    __shared__ unsigned int hist[NBMAX];
    __shared__ unsigned int off[NBMAX];
    __shared__ unsigned int gbase[NBMAX];
    __shared__ unsigned int stg[CTILE];
    __shared__ unsigned int psum[512];
    int tid = threadIdx.x;
    int e0 = blockIdx.x * CTILE;
    int cnt = min(CTILE, E - e0);

    for (int i = tid; i < NBMAX; i += 512) hist[i] = 0;
    __syncthreads();
    for (int i = tid; i < cnt; i += 512)
        atomicAdd(&hist[(unsigned)s_arr[e0 + i] >> 7], 1u);
    __syncthreads();

    unsigned int a0 = hist[2 * tid];
    unsigned int a1 = hist[2 * tid + 1];
    unsigned int ps = a0 + a1;
    unsigned int acc = ps;
    psum[tid] = acc;
    __syncthreads();
    for (int o = 1; o < 512; o <<= 1) {
        unsigned int add = (tid >= o) ? psum[tid - o] : 0;
        __syncthreads();
        acc += add;
        psum[tid] = acc;
        __syncthreads();
    }
    unsigned int exc = acc - ps;
    off[2 * tid]     = exc;
    off[2 * tid + 1] = exc + a0;
    __syncthreads();

    for (int i = tid; i < cnt; i += 512) {
        int s = s_arr[e0 + i];
        int t = t_arr[e0 + i];
        unsigned int bkt = (unsigned)s >> 7;
        unsigned int p = atomicAdd(&off[bkt], 1u);
        stg[p] = ((unsigned)(s & 127) << 17) | (unsigned)t;
    }
    __syncthreads();

    for (int i = tid; i < NBMAX; i += 512) {
        unsigned int h = hist[i];
        gbase[i] = h ? atomicAdd(&gcur[i], h) : 0u;
    }
    __syncthreads();

    int wid = tid >> 6, lane = tid & 63;
    for (int b = wid; b < NBMAX; b += 8) {
        unsigned int h = hist[b];
        if (h == 0) continue;
        unsigned int src = off[b] - h;
        unsigned int dst = gbase[b];
        for (unsigned int i = lane; i < h; i += 64)
            binned[dst + i] = stg[src + i];
    }
}

// ---- 4. qkv GEMM: W in regs, x broadcast from LDS; q stored UNSCALED ----
__global__ void qkv_gemm_kernel(const float* __restrict__ x,
                                const float* __restrict__ W,
                                const float* __restrict__ b,
                                float* __restrict__ qs,
                                unsigned short* __restrict__ kv, int N) {
    int col = threadIdx.x & 127;
    int rw  = threadIdx.x >> 7;
    float w[64];
    #pragma unroll
    for (int k = 0; k < 64; ++k) w[k] = W[k * 128 + col];
    float bias = b[col];
    __shared__ float4 xs[2][16];

    for (int r0 = blockIdx.x * 2; r0 < N; r0 += gridDim.x * 2) {
        __syncthreads();
        if (threadIdx.x < 32) {
            int rr = threadIdx.x >> 4;
            int cc = threadIdx.x & 15;
            int n = r0 + rr;
            xs[rr][cc] = (n < N)
                ? reinterpret_cast<const float4*>(x)[(size_t)n * 16 + cc]
                : make_float4(0.f, 0.f, 0.f, 0.f);
        }
        __syncthreads();
        int n = r0 + rw;
        if (n < N) {
            float acc = bias;
            #pragma unroll
            for (int k4 = 0; k4 < 16; ++k4) {
                float4 xv = xs[rw][k4];
                acc = fmaf(xv.x, w[4 * k4 + 0], acc);
                acc = fmaf(xv.y, w[4 * k4 + 1], acc);
                acc = fmaf(xv.z, w[4 * k4 + 2], acc);
                acc = fmaf(xv.w, w[4 * k4 + 3], acc);
            }
            if (col < 32) {
                qs[(size_t)n * 32 + col] = acc;
            } else if (col < 64) {
                kv[(size_t)n * 96 + (col - 32)] = f2bf(acc);
            } else {
                kv[(size_t)n * 96 + 32 + (col - 64)] = f2bf(acc);
            }
        }
    }
}

// ---- 5. fused per-bucket sort + aggregate ------------------------------
// 1024 threads (16 waves) per 128-node bucket. LDS counting sort of the
// bucket's binned segment, then wave w aggregates nodes [8w, 8w+8) reading
// t-lists from LDS (broadcast) with a 4-wide gather pipeline.
__global__ void __launch_bounds__(1024, 2)
sort_aggregate_kernel(const unsigned int* __restrict__ bbase,
                      const unsigned int* __restrict__ bcnt,
                      const unsigned int* __restrict__ binned,
                      const float* __restrict__ qs,
                      const unsigned int* __restrict__ kv32,
                      float* __restrict__ out, int N) {
    __shared__ unsigned int hist[128];    // per-local-node degree
    __shared__ unsigned int rstart[128];  // local row start
    __shared__ unsigned int cur[128];
    __shared__ unsigned int sh[128];
    __shared__ unsigned int stg[STGMAX];  // node-sorted t values

    int b = blockIdx.x;
    int tid = threadIdx.x;
    unsigned int base = bbase[b];
    unsigned int cnt = min(bcnt[b], (unsigned int)STGMAX);

    if (tid < 128) hist[tid] = 0;
    __syncthreads();
    for (unsigned int i = tid; i < cnt; i += 1024)
        atomicAdd(&hist[binned[base + i] >> 17], 1u);
    __syncthreads();

    // exclusive scan of hist[128] (uniform barriers)
    unsigned int v = (tid < 128) ? hist[tid] : 0;
    unsigned int acc = v;
    if (tid < 128) sh[tid] = acc;
    __syncthreads();
    for (int o = 1; o < 128; o <<= 1) {
        unsigned int add = (tid >= o && tid < 128) ? sh[tid - o] : 0;
        __syncthreads();
        if (tid < 128) { acc += add; sh[tid] = acc; }
        __syncthreads();
    }
    if (tid < 128) {
        unsigned int exc = acc - v;
        rstart[tid] = exc;
        cur[tid] = exc;
    }
    __syncthreads();

    for (unsigned int i = tid; i < cnt; i += 1024) {
        unsigned int e = binned[base + i];
        unsigned int p = atomicAdd(&cur[e >> 17], 1u);
        stg[p] = e & 0x1FFFFu;
    }
    __syncthreads();

    // ---- aggregate: wave w -> local nodes [8w, 8w+8) ----
    int wid = tid >> 6, lane = tid & 63;
    int csrc = (lane < 16) ? (lane & ~3)
             : (lane < 48) ? (((lane - 16) >> 3) << 2)
                           : 0;

    for (int nl = wid * 8; nl < wid * 8 + 8; ++nl) {
        int n = b * 128 + nl;
        if (n >= N) break;
        int dg = (int)hist[nl];
        if (dg == 0) {
            if (lane >= 16 && lane < 48)
                *reinterpret_cast<float2*>(&out[(size_t)n * 64 + 2 * (lane - 16)]) =
                    make_float2(0.f, 0.f);
            continue;
        }
        int start = (int)rstart[nl];
        int end = start + dg;
        float sc = 0.25f * rsqrtf((float)dg);
        float q0 = 0.f, q1 = 0.f;
        if (lane < 16) {
            q0 = qs[(size_t)n * 32 + 2 * lane] * sc;
            q1 = qs[(size_t)n * 32 + 2 * lane + 1] * sc;
        }

        float accx = 0.f, accy = 0.f, den = 0.f;
        int j = start;
        for (; j + 3 < end; j += 4) {
            unsigned int t0 = stg[j], t1 = stg[j + 1];
            unsigned int t2 = stg[j + 2], t3 = stg[j + 3];
            unsigned int r0 = 0, r1 = 0, r2 = 0, r3 = 0;
            if (lane < 48) {
                r0 = kv32[(size_t)t0 * 48 + lane];
                r1 = kv32[(size_t)t1 * 48 + lane];
                r2 = kv32[(size_t)t2 * 48 + lane];
                r3 = kv32[(size_t)t3 * 48 + lane];
            }
            float lo0 = __uint_as_float(r0 << 16), hi0 = __uint_as_float(r0 & 0xffff0000u);
            float lo1 = __uint_as_float(r1 << 16), hi1 = __uint_as_float(r1 & 0xffff0000u);
            float lo2 = __uint_as_float(r2 << 16), hi2 = __uint_as_float(r2 & 0xffff0000u);
            float lo3 = __uint_as_float(r3 << 16), hi3 = __uint_as_float(r3 & 0xffff0000u);
            float p0 = fmaf(q0, lo0, q1 * hi0);
            float p1 = fmaf(q0, lo1, q1 * hi1);
            float p2 = fmaf(q0, lo2, q1 * hi2);
            float p3 = fmaf(q0, lo3, q1 * hi3);
            p0 += __shfl_xor(p0, 1); p0 += __shfl_xor(p0, 2);
            p1 += __shfl_xor(p1, 1); p1 += __shfl_xor(p1, 2);
            p2 += __shfl_xor(p2, 1); p2 += __shfl_xor(p2, 2);
            p3 += __shfl_xor(p3, 1); p3 += __shfl_xor(p3, 2);
            float c0 = __shfl(p0, csrc), c1 = __shfl(p1, csrc);
            float c2 = __shfl(p2, csrc), c3 = __shfl(p3, csrc);
            float w0 = __expf(c0), w1 = __expf(c1);
            float w2 = __expf(c2), w3 = __expf(c3);
            accx = fmaf(w0, lo0, accx); accy = fmaf(w0, hi0, accy);
            accx = fmaf(w1, lo1, accx); accy = fmaf(w1, hi1, accy);
            accx = fmaf(w2, lo2, accx); accy = fmaf(w2, hi2, accy);
            accx = fmaf(w3, lo3, accx); accy = fmaf(w3, hi3, accy);
            den += (w0 + w1) + (w2 + w3);
        }
        for (; j < end; ++j) {
            unsigned int t0 = stg[j];
            unsigned int r0 = 0;
            if (lane < 48) r0 = kv32[(size_t)t0 * 48 + lane];
            float lo0 = __uint_as_float(r0 << 16), hi0 = __uint_as_float(r0 & 0xffff0000u);
            float p0 = fmaf(q0, lo0, q1 * hi0);
            p0 += __shfl_xor(p0, 1); p0 += __shfl_xor(p0, 2);
            float c0 = __shfl(p0, csrc);
            float w0 = __expf(c0);
            accx = fmaf(w0, lo0, accx); accy = fmaf(w0, hi0, accy);
            den += w0;
        }
        if (lane >= 16 && lane < 48) {
            float inv = 1.0f / (den + 1e-16f);
            float2 o = make_float2(accx * inv, accy * inv);
            *reinterpret_cast<float2*>(&out[(size_t)n * 64 + 2 * (lane - 16)]) = o;
        }
    }
}

extern "C" void kernel_launch(void* const* d_in, const int* in_sizes, int n_in,
                              void* d_out, int out_size, void* d_ws, size_t ws_size,
                              hipStream_t stream) {
    const float* x = (const float*)d_in[0];
    const int*   eidx = (const int*)d_in[1];
    const float* W = (const float*)d_in[2];
    const float* b = (const float*)d_in[3];
    int N = in_sizes[0] / NDIM;
    int E = in_sizes[1] / 2;
    float* out = (float*)d_out;

    int NB = (N + 127) / 128;           // 782

    // workspace layout
    float* qs = (float*)d_ws;                                     // N*32 f
    unsigned short* kv = (unsigned short*)(qs + (size_t)N * 32);  // N*96 u16
    unsigned int* bcnt  = (unsigned int*)(kv + (size_t)N * 96);   // NBMAX
    unsigned int* bbase = bcnt + NBMAX;                           // NBMAX
    unsigned int* gcur  = bbase + NBMAX;                          // NBMAX
    unsigned int* binned = gcur + NBMAX;                          // E u32

    const int* s_arr = eidx;
    const int* t_arr = eidx + E;

    hipMemsetAsync(bcnt, 0, NBMAX * sizeof(unsigned int), stream);

    bucket_count_kernel<<<256, 256, 0, stream>>>(s_arr, bcnt, E);
    scan_buckets_kernel<<<1, 1024, 0, stream>>>(bcnt, bbase, gcur);
    bin_kernel<<<(E + CTILE - 1) / CTILE, 512, 0, stream>>>(s_arr, t_arr, gcur, binned, E);
    qkv_gemm_kernel<<<2048, 256, 0, stream>>>(x, W, b, qs, kv, N);
    sort_aggregate_kernel<<<NB, 1024, 0, stream>>>(
        bbase, bcnt, binned, qs, (const unsigned int*)kv, out, N);
}

// Round 6
// 177.032 us; speedup vs baseline: 3.4800x; 1.1079x over previous
//
#include <hip/hip_runtime.h>

// Graph transformer conv on MI355X. N=100000, E=1.6M, DIM=64, H=4, D=8.
// Round 6: MLP + machine-fill fixes. 8-wide gather unroll in aggregate,
// 1024-thread bin kernel, GEMM with 8 rows per barrier.

#define NDIM 64
#define NBMAX 1024      // buckets of 128 nodes
#define CTILE 8192
#define STGMAX 4352     // per-bucket edge capacity (mean 2048, sd ~45)

static __device__ __forceinline__ unsigned short f2bf(float f) {
    unsigned int u = __float_as_uint(f);
    unsigned int r = (u + 0x7fffu + ((u >> 16) & 1u)) >> 16;  // RNE
    return (unsigned short)r;
}

// ---- 1. count edges per 128-node bucket --------------------------------
__global__ void bucket_count_kernel(const int* __restrict__ s_arr,
                                    unsigned int* __restrict__ bcnt, int E) {
    __shared__ unsigned int h[NBMAX];
    for (int i = threadIdx.x; i < NBMAX; i += blockDim.x) h[i] = 0;
    __syncthreads();
    int i0 = blockIdx.x * blockDim.x + threadIdx.x;
    int st = gridDim.x * blockDim.x;
    for (int e = i0; e < E; e += st)
        atomicAdd(&h[(unsigned)s_arr[e] >> 7], 1u);
    __syncthreads();
    for (int i = threadIdx.x; i < NBMAX; i += blockDim.x)
        if (h[i]) atomicAdd(&bcnt[i], h[i]);
}

// ---- 2. exclusive scan of bucket counts --------------------------------
__global__ void scan_buckets_kernel(const unsigned int* __restrict__ bcnt,
                                    unsigned int* __restrict__ bbase,
                                    unsigned int* __restrict__ gcur) {
    __shared__ unsigned int sh[1024];
    int tid = threadIdx.x;
    unsigned int v = bcnt[tid];
    unsigned int acc = v;
    sh[tid] = acc;
    __syncthreads();
    for (int off = 1; off < 1024; off <<= 1) {
        unsigned int add = (tid >= off) ? sh[tid - off] : 0;
        __syncthreads();
        acc += add;
        sh[tid] = acc;
        __syncthreads();
    }
    bbase[tid] = acc - v;
    gcur[tid]  = acc - v;
}

// ---- 3. bin edges into bucket-major order, chunk-coalesced -------------
// 1024 threads per 8192-edge tile: LDS counting sort by bucket, per-bucket
// global reservation, wave-coalesced segment copy.
__global__ void __launch_bounds__(1024, 2)
bin_kernel(const int* __restrict__ s_arr,
           const int* __restrict__ t_arr,
           unsigned int* __restrict__ gcur,
           unsigned int* __restrict__ binned, int E) {
    __shared__ unsigned int hist[NBMAX];
    __shared__ unsigned int off[NBMAX];
    __shared__ unsigned int gbase[NBMAX];
    __shared__ unsigned int stg[CTILE];
    __shared__ unsigned int psum[NBMAX];
    int tid = threadIdx.x;
    int e0 = blockIdx.x * CTILE;
    int cnt = min(CTILE, E - e0);

    hist[tid] = 0;
    __syncthreads();
    for (int i = tid; i < cnt; i += 1024)
        atomicAdd(&hist[(unsigned)s_arr[e0 + i] >> 7], 1u);
    __syncthreads();

    // exclusive scan of hist[1024] with 1024 threads (Hillis-Steele)
    unsigned int v = hist[tid];
    unsigned int acc = v;
    psum[tid] = acc;
    __syncthreads();
    for (int o = 1; o < 1024; o <<= 1) {
        unsigned int add = (tid >= o) ? psum[tid - o] : 0;
        __syncthreads();
        acc += add;
        psum[tid] = acc;
        __syncthreads();
    }
    off[tid] = acc - v;
    __syncthreads();

    for (int i = tid; i < cnt; i += 1024) {
        int s = s_arr[e0 + i];
        int t = t_arr[e0 + i];
        unsigned int bkt = (unsigned)s >> 7;
        unsigned int p = atomicAdd(&off[bkt], 1u);
        stg[p] = ((unsigned)(s & 127) << 17) | (unsigned)t;
    }
    __syncthreads();

    {
        unsigned int h = hist[tid];
        gbase[tid] = h ? atomicAdd(&gcur[tid], h) : 0u;
    }
    __syncthreads();

    int wid = tid >> 6, lane = tid & 63;
    for (int b = wid; b < NBMAX; b += 16) {
        unsigned int h = hist[b];
        if (h == 0) continue;
        unsigned int src = off[b] - h;
        unsigned int dst = gbase[b];
        for (unsigned int i = lane; i < h; i += 64)
            binned[dst + i] = stg[src + i];
    }
}

// ---- 4. qkv GEMM: W in regs, x broadcast from LDS, 8 rows per barrier ---
__global__ void qkv_gemm_kernel(const float* __restrict__ x,
                                const float* __restrict__ W,
                                const float* __restrict__ b,
                                float* __restrict__ qs,
                                unsigned short* __restrict__ kv, int N) {
    int col = threadIdx.x & 127;
    int rw  = threadIdx.x >> 7;    // 0/1: rows 0-3 or 4-7 of the tile
    float w[64];
    #pragma unroll
    for (int k = 0; k < 64; ++k) w[k] = W[k * 128 + col];
    float bias = b[col];
    __shared__ float4 xs[8][16];

    for (int r0 = blockIdx.x * 8; r0 < N; r0 += gridDim.x * 8) {
        __syncthreads();
        if (threadIdx.x < 128) {
            int rr = threadIdx.x >> 4;
            int cc = threadIdx.x & 15;
            int n = r0 + rr;
            xs[rr][cc] = (n < N)
                ? reinterpret_cast<const float4*>(x)[(size_t)n * 16 + cc]
                : make_float4(0.f, 0.f, 0.f, 0.f);
        }
        __syncthreads();
        #pragma unroll
        for (int rsub = 0; rsub < 4; ++rsub) {
            int rr = rw * 4 + rsub;
            int n = r0 + rr;
            if (n < N) {
                float acc = bias;
                #pragma unroll
                for (int k4 = 0; k4 < 16; ++k4) {
                    float4 xv = xs[rr][k4];
                    acc = fmaf(xv.x, w[4 * k4 + 0], acc);
                    acc = fmaf(xv.y, w[4 * k4 + 1], acc);
                    acc = fmaf(xv.z, w[4 * k4 + 2], acc);
                    acc = fmaf(xv.w, w[4 * k4 + 3], acc);
                }
                if (col < 32) {
                    qs[(size_t)n * 32 + col] = acc;
                } else if (col < 64) {
                    kv[(size_t)n * 96 + (col - 32)] = f2bf(acc);
                } else {
                    kv[(size_t)n * 96 + 32 + (col - 64)] = f2bf(acc);
                }
            }
        }
    }
}

// ---- 5. fused per-bucket sort + aggregate, 8-wide gather pipeline ------
__global__ void __launch_bounds__(1024, 2)
sort_aggregate_kernel(const unsigned int* __restrict__ bbase,
                      const unsigned int* __restrict__ bcnt,
                      const unsigned int* __restrict__ binned,
                      const float* __restrict__ qs,
                      const unsigned int* __restrict__ kv32,
                      float* __restrict__ out, int N) {
    __shared__ unsigned int hist[128];
    __shared__ unsigned int rstart[128];
    __shared__ unsigned int cur[128];
    __shared__ unsigned int sh[128];
    __shared__ unsigned int stg[STGMAX];

    int b = blockIdx.x;
    int tid = threadIdx.x;
    unsigned int base = bbase[b];
    unsigned int cnt = min(bcnt[b], (unsigned int)STGMAX);

    if (tid < 128) hist[tid] = 0;
    __syncthreads();
    for (unsigned int i = tid; i < cnt; i += 1024)
        atomicAdd(&hist[binned[base + i] >> 17], 1u);
    __syncthreads();

    unsigned int v = (tid < 128) ? hist[tid] : 0;
    unsigned int acc = v;
    if (tid < 128) sh[tid] = acc;
    __syncthreads();
    for (int o = 1; o < 128; o <<= 1) {
        unsigned int add = (tid >= o && tid < 128) ? sh[tid - o] : 0;
        __syncthreads();
        if (tid < 128) { acc += add; sh[tid] = acc; }
        __syncthreads();
    }
    if (tid < 128) {
        unsigned int exc = acc - v;
        rstart[tid] = exc;
        cur[tid] = exc;
    }
    __syncthreads();

    for (unsigned int i = tid; i < cnt; i += 1024) {
        unsigned int e = binned[base + i];
        unsigned int p = atomicAdd(&cur[e >> 17], 1u);
        stg[p] = e & 0x1FFFFu;
    }
    __syncthreads();

    int wid = tid >> 6, lane = tid & 63;
    unsigned int ulane = (unsigned int)lane;
    int csrc = (lane < 16) ? (lane & ~3)
             : (lane < 48) ? (((lane - 16) >> 3) << 2)
                           : 0;

    for (int nl = wid * 8; nl < wid * 8 + 8; ++nl) {
        int n = b * 128 + nl;
        if (n >= N) break;
        int dg = (int)hist[nl];
        if (dg == 0) {
            if (lane >= 16 && lane < 48)
                *reinterpret_cast<float2*>(&out[(size_t)n * 64 + 2 * (lane - 16)]) =
                    make_float2(0.f, 0.f);
            continue;
        }
        int start = (int)rstart[nl];
        int end = start + dg;
        float sc = 0.25f * rsqrtf((float)dg);
        float q0 = 0.f, q1 = 0.f;
        if (lane < 16) {
            q0 = qs[(size_t)n * 32 + 2 * lane] * sc;
            q1 = qs[(size_t)n * 32 + 2 * lane + 1] * sc;
        }

        float accx = 0.f, accy = 0.f, den = 0.f;
        int j = start;
        for (; j + 7 < end; j += 8) {
            unsigned int t[8], r[8];
            #pragma unroll
            for (int i = 0; i < 8; ++i) t[i] = stg[j + i];
            #pragma unroll
            for (int i = 0; i < 8; ++i)
                r[i] = (lane < 48) ? kv32[t[i] * 48u + ulane] : 0u;
            float lo[8], hi[8], p[8];
            #pragma unroll
            for (int i = 0; i < 8; ++i) {
                lo[i] = __uint_as_float(r[i] << 16);
                hi[i] = __uint_as_float(r[i] & 0xffff0000u);
                p[i] = fmaf(q0, lo[i], q1 * hi[i]);
            }
            #pragma unroll
            for (int i = 0; i < 8; ++i) {
                p[i] += __shfl_xor(p[i], 1);
                p[i] += __shfl_xor(p[i], 2);
            }
            #pragma unroll
            for (int i = 0; i < 8; ++i) {
                float c = __shfl(p[i], csrc);
                float w = __expf(c);
                accx = fmaf(w, lo[i], accx);
                accy = fmaf(w, hi[i], accy);
                den += w;
            }
        }
        for (; j + 3 < end; j += 4) {
            unsigned int t[4], r[4];
            #pragma unroll
            for (int i = 0; i < 4; ++i) t[i] = stg[j + i];
            #pragma unroll
            for (int i = 0; i < 4; ++i)
                r[i] = (lane < 48) ? kv32[t[i] * 48u + ulane] : 0u;
            #pragma unroll
            for (int i = 0; i < 4; ++i) {
                float lo = __uint_as_float(r[i] << 16);
                float hi = __uint_as_float(r[i] & 0xffff0000u);
                float p = fmaf(q0, lo, q1 * hi);
                p += __shfl_xor(p, 1);
                p += __shfl_xor(p, 2);
                float c = __shfl(p, csrc);
                float w = __expf(c);
                accx = fmaf(w, lo, accx);
                accy = fmaf(w, hi, accy);
                den += w;
            }
        }
        for (; j < end; ++j) {
            unsigned int t0 = stg[j];
            unsigned int r0 = (lane < 48) ? kv32[t0 * 48u + ulane] : 0u;
            float lo = __uint_as_float(r0 << 16);
            float hi = __uint_as_float(r0 & 0xffff0000u);
            float p = fmaf(q0, lo, q1 * hi);
            p += __shfl_xor(p, 1);
            p += __shfl_xor(p, 2);
            float c = __shfl(p, csrc);
            float w = __expf(c);
            accx = fmaf(w, lo, accx);
            accy = fmaf(w, hi, accy);
            den += w;
        }
        if (lane >= 16 && lane < 48) {
            float inv = 1.0f / (den + 1e-16f);
            float2 o = make_float2(accx * inv, accy * inv);
            *reinterpret_cast<float2*>(&out[(size_t)n * 64 + 2 * (lane - 16)]) = o;
        }
    }
}

extern "C" void kernel_launch(void* const* d_in, const int* in_sizes, int n_in,
                              void* d_out, int out_size, void* d_ws, size_t ws_size,
                              hipStream_t stream) {
    const float* x = (const float*)d_in[0];
    const int*   eidx = (const int*)d_in[1];
    const float* W = (const float*)d_in[2];
    const float* b = (const float*)d_in[3];
    int N = in_sizes[0] / NDIM;
    int E = in_sizes[1] / 2;
    float* out = (float*)d_out;

    int NB = (N + 127) / 128;           // 782

    // workspace layout
    float* qs = (float*)d_ws;                                     // N*32 f
    unsigned short* kv = (unsigned short*)(qs + (size_t)N * 32);  // N*96 u16
    unsigned int* bcnt  = (unsigned int*)(kv + (size_t)N * 96);   // NBMAX
    unsigned int* bbase = bcnt + NBMAX;                           // NBMAX
    unsigned int* gcur  = bbase + NBMAX;                          // NBMAX
    unsigned int* binned = gcur + NBMAX;                          // E u32

    const int* s_arr = eidx;
    const int* t_arr = eidx + E;

    hipMemsetAsync(bcnt, 0, NBMAX * sizeof(unsigned int), stream);

    bucket_count_kernel<<<512, 256, 0, stream>>>(s_arr, bcnt, E);
    scan_buckets_kernel<<<1, 1024, 0, stream>>>(bcnt, bbase, gcur);
    bin_kernel<<<(E + CTILE - 1) / CTILE, 1024, 0, stream>>>(s_arr, t_arr, gcur, binned, E);
    qkv_gemm_kernel<<<2048, 256, 0, stream>>>(x, W, b, qs, kv, N);
    sort_aggregate_kernel<<<NB, 1024, 0, stream>>>(
        bbase, bcnt, binned, qs, (const unsigned int*)kv, out, N);
}